// Round 2
// baseline (31238.177 us; speedup 1.0000x reference)
//
#include <hip/hip_runtime.h>
#include <stdint.h>
#include <limits.h>

// Problem constants (match reference)
#define T_STEPS 100
#define BSZ 512
#define HL 1024
#define HC 256
#define EMB 256
#define VOC 32000
#define NCHUNK 250           // VOC / 128
#define KCAT 1536            // E + HC + HL
#define NCAT 4096            // r/z fused (2048) + gi_n (1024) + gh_n (1024)

typedef __attribute__((ext_vector_type(8))) short short8;
typedef __attribute__((ext_vector_type(4))) float f32x4;
typedef __attribute__((ext_vector_type(4))) unsigned short u16x4;
#define MFMA16(a, b, c) __builtin_amdgcn_mfma_f32_16x16x32_bf16(a, b, c, 0, 0, 0)

// 6-term product of triple-split operands: residual ~2^-24 (fp32-class)
#define ACC6(acc, ah, am, al, bh, bm, bl) \
  { acc = MFMA16(ah, bh, acc); acc = MFMA16(ah, bm, acc); acc = MFMA16(am, bh, acc); \
    acc = MFMA16(ah, bl, acc); acc = MFMA16(am, bm, acc); acc = MFMA16(al, bh, acc); }

// ---------------- threefry2x32 (JAX-exact, partitionable variant verified R1) ----------------
__device__ __forceinline__ void threefry2x32(uint32_t k0, uint32_t k1,
                                             uint32_t x0, uint32_t x1,
                                             uint32_t& o0, uint32_t& o1) {
  uint32_t ks2 = k0 ^ k1 ^ 0x1BD11BDAu;
  x0 += k0; x1 += k1;
#define TF_R(x, r) (((x) << (r)) | ((x) >> (32 - (r))))
#define TF_RND(r) { x0 += x1; x1 = TF_R(x1, r); x1 ^= x0; }
  TF_RND(13) TF_RND(15) TF_RND(26) TF_RND(6)
  x0 += k1; x1 += ks2 + 1u;
  TF_RND(17) TF_RND(29) TF_RND(16) TF_RND(24)
  x0 += ks2; x1 += k0 + 2u;
  TF_RND(13) TF_RND(15) TF_RND(26) TF_RND(6)
  x0 += k0; x1 += k1 + 3u;
  TF_RND(17) TF_RND(29) TF_RND(16) TF_RND(24)
  x0 += k1; x1 += ks2 + 4u;
  TF_RND(13) TF_RND(15) TF_RND(26) TF_RND(6)
  x0 += ks2; x1 += k0 + 5u;
#undef TF_RND
#undef TF_R
  o0 = x0; o1 = x1;
}

__device__ __forceinline__ float gumbel_from_u32(uint32_t bits) {
  float f = __uint_as_float((bits >> 9) | 0x3f800000u) - 1.0f;
  f = fmaxf(f, 1.17549435e-38f);
  return -logf(-logf(f));
}

__device__ __forceinline__ float read_temp(const int* p) {
  int v = *p;
  if (v >= -(1 << 24) && v <= (1 << 24)) return (float)v;
  return __int_as_float(v);
}

__device__ __forceinline__ unsigned short f2bf(float x) {
  uint32_t u = __float_as_uint(x);
  u += 0x7fffu + ((u >> 16) & 1u);
  return (unsigned short)(u >> 16);
}
__device__ __forceinline__ float bf2f(unsigned short h) {
  return __uint_as_float(((uint32_t)h) << 16);
}
__device__ __forceinline__ void split3(float x, unsigned short& h,
                                       unsigned short& m, unsigned short& l) {
  h = f2bf(x);
  float r = x - bf2f(h);     // exact
  m = f2bf(r);
  r = r - bf2f(m);           // exact
  l = f2bf(r);
}

// ---------------- fp32 -> bf16 triple split (once per launch: emb) ----------------
__global__ __launch_bounds__(256) void k_split3(const float* __restrict__ src,
                                                unsigned short* __restrict__ hi,
                                                unsigned short* __restrict__ mid,
                                                unsigned short* __restrict__ lo,
                                                int n4) {
  int i = blockIdx.x * 256 + threadIdx.x;
  if (i >= n4) return;
  float4 v = ((const float4*)src)[i];
  float vv[4] = {v.x, v.y, v.z, v.w};
  u16x4 h, m, l;
#pragma unroll
  for (int j = 0; j < 4; j++) {
    unsigned short a, b, c;
    split3(vv[j], a, b, c);
    h[j] = a; m[j] = b; l[j] = c;
  }
  ((u16x4*)hi)[i] = h;
  ((u16x4*)mid)[i] = m;
  ((u16x4*)lo)[i] = l;
}

// ---------------- W_cat assembly + split (once per launch) ----------------
// Wc [4096][1536]: n'<2048 (r,z):  [0:512)=w_ih[n'], [512:1536)=w_hh[n']
//                  n' in [2048,3072) (gi_n): [0:512)=w_ih[n'], rest 0
//                  n' in [3072,4096) (gh_n): [512:1536)=w_hh[n'-1024], rest 0
__global__ __launch_bounds__(256) void k_wprep(const float* __restrict__ w_ih,
                                               const float* __restrict__ w_hh,
                                               unsigned short* __restrict__ wch,
                                               unsigned short* __restrict__ wcm,
                                               unsigned short* __restrict__ wcl) {
  int i4 = blockIdx.x * 256 + threadIdx.x;     // 0 .. 4096*1536/4-1
  if (i4 >= NCAT * KCAT / 4) return;
  int idx = i4 * 4;
  int n = idx / KCAT;
  int k = idx - n * KCAT;
  float4 v;
  if (k < 512) {
    if (n < 3072) v = *(const float4*)&w_ih[(size_t)n * 512 + k];
    else          v = (float4){0.f, 0.f, 0.f, 0.f};
  } else {
    int g = n >> 10;
    if (g < 2)       v = *(const float4*)&w_hh[(size_t)n * 1024 + (k - 512)];
    else if (g == 3) v = *(const float4*)&w_hh[(size_t)(n - 1024) * 1024 + (k - 512)];
    else             v = (float4){0.f, 0.f, 0.f, 0.f};
  }
  float vv[4] = {v.x, v.y, v.z, v.w};
  u16x4 h, m, l;
#pragma unroll
  for (int j = 0; j < 4; j++) {
    unsigned short a, b, c;
    split3(vv[j], a, b, c);
    h[j] = a; m[j] = b; l[j] = c;
  }
  size_t o = (size_t)n * KCAT + k;
  *(u16x4*)(wch + o) = h;
  *(u16x4*)(wcm + o) = m;
  *(u16x4*)(wcl + o) = l;
}

// ---------------- init: keys, token copy, H0 copy, fused bias ----------------
__global__ __launch_bounds__(256) void k_init(const float* __restrict__ lang_h0,
                                              const int* __restrict__ inpt0,
                                              const float* __restrict__ b_ih,
                                              const float* __restrict__ b_hh,
                                              uint32_t* __restrict__ keys,
                                              int* __restrict__ cur_tok,
                                              float* __restrict__ H0,
                                              float* __restrict__ bc) {
  int idx = blockIdx.x * 256 + threadIdx.x;
  if (idx < T_STEPS) {
    uint32_t o0, o1;
    threefry2x32(0u, 1u, 0u, (uint32_t)idx, o0, o1);
    keys[2 * idx] = o0; keys[2 * idx + 1] = o1;
  }
  if (idx < BSZ) cur_tok[idx] = inpt0[idx];
  if (idx < NCAT) {
    int g = idx >> 10;
    float v;
    if (g < 2)       v = b_ih[idx] + b_hh[idx];  // r,z fused
    else if (g == 2) v = b_ih[idx];              // gi_n
    else             v = b_hh[idx - 1024];       // gh_n
    bc[idx] = v;
  }
  if (idx < BSZ * HL) H0[idx] = lang_h0[idx];
}

// ---------------- per-step A assembly: [emb[tok] | ctx | Hin] triple-split ----------------
__global__ __launch_bounds__(256) void k_xsplit(const float* __restrict__ emb,
                                                const float* __restrict__ ctx,
                                                const int* __restrict__ tok,
                                                const float* __restrict__ Hin,
                                                unsigned short* __restrict__ xh,
                                                unsigned short* __restrict__ xm,
                                                unsigned short* __restrict__ xl) {
  int i4 = blockIdx.x * 256 + threadIdx.x;     // 0 .. 512*1536/4-1
  if (i4 >= BSZ * KCAT / 4) return;
  int idx = i4 * 4;
  int b = idx / KCAT;
  int k = idx - b * KCAT;
  const float* src;
  if (k < 256)      src = emb + (size_t)tok[b] * 256 + k;
  else if (k < 512) src = ctx + (size_t)b * 256 + (k - 256);
  else              src = Hin + (size_t)b * 1024 + (k - 512);
  float4 v = *(const float4*)src;
  float vv[4] = {v.x, v.y, v.z, v.w};
  u16x4 h, m, l;
#pragma unroll
  for (int j = 0; j < 4; j++) {
    unsigned short a, bb, c;
    split3(vv[j], a, bb, c);
    h[j] = a; m[j] = bb; l[j] = c;
  }
  size_t o = (size_t)b * KCAT + k;
  *(u16x4*)(xh + o) = h;
  *(u16x4*)(xm + o) = m;
  *(u16x4*)(xl + o) = l;
}

// ---------------- fused GI+GH GEMM, 6-term MFMA ----------------
// grid (4096/64=64, 512/64=8), 256 thr = 4 waves. Wave: 16 b x 64 n'.
// Gate-aligned x-blocks clamp k-range: r/z K=[0,1536), gi_n K=[0,512), gh_n K=[512,1536).
__global__ __launch_bounds__(256) void k_big(
    const unsigned short* __restrict__ xh, const unsigned short* __restrict__ xm,
    const unsigned short* __restrict__ xl,
    const unsigned short* __restrict__ wch, const unsigned short* __restrict__ wcm,
    const unsigned short* __restrict__ wcl,
    const float* __restrict__ bc, float* __restrict__ Gp) {
  int tid = threadIdx.x;
  int wave = tid >> 6, lane = tid & 63;
  int ml = lane & 15, quad = lane >> 4;
  int n0 = blockIdx.x * 64;
  int gate = n0 >> 10;
  int kbeg = (gate == 3) ? 512 : 0;
  int kend = (gate == 2) ? 512 : KCAT;
  int bA = blockIdx.y * 64 + wave * 16 + ml;
  f32x4 acc[4];
#pragma unroll
  for (int tn = 0; tn < 4; tn++) acc[tn] = (f32x4){0.f, 0.f, 0.f, 0.f};

  for (int k0 = kbeg; k0 < kend; k0 += 32) {
    int k = k0 + quad * 8;
    size_t aoff = (size_t)bA * KCAT + k;
    short8 ah = *(const short8*)(xh + aoff);
    short8 am_ = *(const short8*)(xm + aoff);
    short8 al = *(const short8*)(xl + aoff);
#pragma unroll
    for (int tn = 0; tn < 4; tn++) {
      int n = n0 + tn * 16 + ml;
      size_t off = (size_t)n * KCAT + k;
      short8 bh = *(const short8*)(wch + off);
      short8 bm = *(const short8*)(wcm + off);
      short8 bl = *(const short8*)(wcl + off);
      ACC6(acc[tn], ah, am_, al, bh, bm, bl);
    }
  }
  // C layout: col = lane&15 (n'), row = quad*4+reg (b)
  int brow = blockIdx.y * 64 + wave * 16 + quad * 4;
#pragma unroll
  for (int tn = 0; tn < 4; tn++) {
    int n = n0 + tn * 16 + ml;
    float bias = bc[n];
#pragma unroll
    for (int reg = 0; reg < 4; reg++)
      Gp[(size_t)(brow + reg) * NCAT + n] = acc[tn][reg] + bias;
  }
}

// ---------------- pointwise GRU gates -> Hout ----------------
__global__ __launch_bounds__(256) void k_point(const float* __restrict__ Gp,
                                               const float* __restrict__ Hin,
                                               float* __restrict__ Hout) {
  int i4 = blockIdx.x * 256 + threadIdx.x;     // 0 .. 512*1024/4-1
  if (i4 >= BSZ * HL / 4) return;
  int idx = i4 * 4;
  int b = idx >> 10, i = idx & 1023;
  const float* g = Gp + (size_t)b * NCAT;
  float4 gr = *(const float4*)(g + i);
  float4 gz = *(const float4*)(g + 1024 + i);
  float4 gn = *(const float4*)(g + 2048 + i);
  float4 gh = *(const float4*)(g + 3072 + i);
  float4 h4 = *(const float4*)(Hin + (size_t)b * 1024 + i);
  float grv[4] = {gr.x, gr.y, gr.z, gr.w};
  float gzv[4] = {gz.x, gz.y, gz.z, gz.w};
  float gnv[4] = {gn.x, gn.y, gn.z, gn.w};
  float ghv[4] = {gh.x, gh.y, gh.z, gh.w};
  float hv[4] = {h4.x, h4.y, h4.z, h4.w};
  float ov[4];
#pragma unroll
  for (int j = 0; j < 4; j++) {
    float r = 1.0f / (1.0f + expf(-grv[j]));
    float z = 1.0f / (1.0f + expf(-gzv[j]));
    float n = tanhf(gnv[j] + r * ghv[j]);
    ov[j] = (1.0f - z) * n + z * hv[j];
  }
  float4 o; o.x = ov[0]; o.y = ov[1]; o.z = ov[2]; o.w = ov[3];
  *(float4*)&Hout[(size_t)b * 1024 + i] = o;
}

// ---------------- dec GEMM (fp32) + fused triple-split output ----------------
// grid (256/64=4, 512/16=32), 256 thr. Block: 16 b x 64 cols, K=1024.
__global__ __launch_bounds__(256) void k_dec(const float* __restrict__ H,
                                             const float* __restrict__ dec_W,
                                             const float* __restrict__ dec_b,
                                             unsigned short* __restrict__ dh,
                                             unsigned short* __restrict__ dm,
                                             unsigned short* __restrict__ dl) {
  __shared__ __align__(16) float As[32][20];
  __shared__ __align__(16) float Ws[32][68];
  int tid = threadIdx.x;
  int tb = tid >> 4;          // 0..15 = b row
  int tv = tid & 15;          // 4 cols: tv*4
  int col0 = blockIdx.x * 64, row0 = blockIdx.y * 16;
  int srw = tid >> 3;         // 0..31
  int kq = (tid & 7) * 4;
  float acc[4] = {};
  for (int k0 = 0; k0 < 1024; k0 += 32) {
    if (srw < 16) {           // As: 16 rows x 32 k
      float4 a4 = *(const float4*)&H[(size_t)(row0 + srw) * 1024 + k0 + kq];
      As[kq + 0][srw] = a4.x; As[kq + 1][srw] = a4.y; As[kq + 2][srw] = a4.z; As[kq + 3][srw] = a4.w;
    }
    // Ws: 64 rows x 32 k — rows srw and srw+32
#pragma unroll
    for (int i = 0; i < 2; i++) {
      int r = srw + 32 * i;
      float4 w4 = *(const float4*)&dec_W[(size_t)(col0 + r) * 1024 + k0 + kq];
      Ws[kq + 0][r] = w4.x; Ws[kq + 1][r] = w4.y;
      Ws[kq + 2][r] = w4.z; Ws[kq + 3][r] = w4.w;
    }
    __syncthreads();
#pragma unroll
    for (int kk = 0; kk < 32; kk++) {
      float a = As[kk][tb];
      float4 w = *(float4*)&Ws[kk][tv * 4];
      float wv[4] = {w.x, w.y, w.z, w.w};
#pragma unroll
      for (int j = 0; j < 4; j++) acc[j] += a * wv[j];
    }
    __syncthreads();
  }
  int col = col0 + tv * 4;
  float4 b4 = *(const float4*)&dec_b[col];
  float bv[4] = {b4.x, b4.y, b4.z, b4.w};
  u16x4 h, m, l;
#pragma unroll
  for (int j = 0; j < 4; j++) {
    unsigned short a, b, c;
    split3(acc[j] + bv[j], a, b, c);
    h[j] = a; m[j] = b; l[j] = c;
  }
  size_t o = (size_t)(row0 + tb) * 256 + col;
  *(u16x4*)(dh + o) = h;
  *(u16x4*)(dm + o) = m;
  *(u16x4*)(dl + o) = l;
}

// ---------------- logits 6-term MFMA + gumbel + per-chunk argmax ----------------
// grid (250, 4), 256 thr = 4 waves. Block: 128 b x 128 v; wave: 32 b (2 m-tiles) x 128 v.
__global__ __launch_bounds__(256) void k_logits(const unsigned short* __restrict__ dh,
                                                const unsigned short* __restrict__ dm,
                                                const unsigned short* __restrict__ dl,
                                                const unsigned short* __restrict__ ebh,
                                                const unsigned short* __restrict__ ebm,
                                                const unsigned short* __restrict__ ebl,
                                                const uint32_t* __restrict__ keys,
                                                int t,
                                                const int* __restrict__ temp_ptr,
                                                float* __restrict__ pval,
                                                int* __restrict__ pidx) {
  __shared__ __align__(16) unsigned short Eh[128 * 40];
  __shared__ __align__(16) unsigned short Em[128 * 40];
  __shared__ __align__(16) unsigned short El[128 * 40];
  int tid = threadIdx.x;
  int wave = tid >> 6, lane = tid & 63;
  int ml = lane & 15, quad = lane >> 4;
  int c = blockIdx.x;
  int v0 = c * 128;
  int b0 = blockIdx.y * 128;
  f32x4 acc[2][8];
#pragma unroll
  for (int mi = 0; mi < 2; mi++)
#pragma unroll
    for (int tv = 0; tv < 8; tv++) acc[mi][tv] = (f32x4){0.f, 0.f, 0.f, 0.f};

  for (int k0 = 0; k0 < 256; k0 += 32) {
    __syncthreads();
    // stage pre-split emb tile [128 v][32 k] — pure copy
#pragma unroll
    for (int i = 0; i < 4; i++) {
      int idx4 = tid + i * 256;          // 0..1023 u16x4 slots
      int v = idx4 >> 3;
      int k4 = (idx4 & 7) * 4;
      size_t go = (size_t)(v0 + v) * 256 + k0 + k4;
      *(u16x4*)&Eh[v * 40 + k4] = *(const u16x4*)(ebh + go);
      *(u16x4*)&Em[v * 40 + k4] = *(const u16x4*)(ebm + go);
      *(u16x4*)&El[v * 40 + k4] = *(const u16x4*)(ebl + go);
    }
    __syncthreads();
    // A fragments (dec triple-split, global; L2-resident)
    short8 ah[2], am_[2], al[2];
#pragma unroll
    for (int mi = 0; mi < 2; mi++) {
      int brow = b0 + wave * 32 + mi * 16 + ml;
      size_t off = (size_t)brow * 256 + k0 + quad * 8;
      ah[mi] = *(const short8*)(dh + off);
      am_[mi] = *(const short8*)(dm + off);
      al[mi] = *(const short8*)(dl + off);
    }
#pragma unroll
    for (int tv = 0; tv < 8; tv++) {
      int lo = (tv * 16 + ml) * 40 + quad * 8;
      short8 bh = *(const short8*)&Eh[lo];
      short8 bm = *(const short8*)&Em[lo];
      short8 bl = *(const short8*)&El[lo];
#pragma unroll
      for (int mi = 0; mi < 2; mi++)
        ACC6(acc[mi][tv], ah[mi], am_[mi], al[mi], bh, bm, bl);
    }
  }
  float temp = read_temp(temp_ptr);
  uint32_t kk0 = keys[2 * t], kk1 = keys[2 * t + 1];
#pragma unroll
  for (int mi = 0; mi < 2; mi++) {
    float best[4];
    int bidx[4];
#pragma unroll
    for (int reg = 0; reg < 4; reg++) { best[reg] = -3.402823466e38f; bidx[reg] = INT_MAX; }
    // C layout: col (v) = lane&15, row (b) = quad*4+reg
#pragma unroll
    for (int tv = 0; tv < 8; tv++) {
      int v = v0 + tv * 16 + ml;
#pragma unroll
      for (int reg = 0; reg < 4; reg++) {
        int b = b0 + wave * 32 + mi * 16 + quad * 4 + reg;
        uint32_t o0, o1;
        threefry2x32(kk0, kk1, 0u, (uint32_t)(b * VOC + v), o0, o1);
        float s = acc[mi][tv][reg] / temp + gumbel_from_u32(o0 ^ o1);
        if (s > best[reg]) { best[reg] = s; bidx[reg] = v; }
      }
    }
#pragma unroll
    for (int off = 1; off < 16; off <<= 1) {
#pragma unroll
      for (int reg = 0; reg < 4; reg++) {
        float ov = __shfl_xor(best[reg], off, 64);
        int oi = __shfl_xor(bidx[reg], off, 64);
        if (ov > best[reg] || (ov == best[reg] && oi < bidx[reg])) {
          best[reg] = ov; bidx[reg] = oi;
        }
      }
    }
    if (ml == 0) {
#pragma unroll
      for (int reg = 0; reg < 4; reg++) {
        int b = b0 + wave * 32 + mi * 16 + quad * 4 + reg;
        pval[(size_t)b * NCHUNK + c] = best[reg];
        pidx[(size_t)b * NCHUNK + c] = bidx[reg];
      }
    }
  }
}

// ---------------- final argmax over chunks ----------------
__global__ __launch_bounds__(256) void k_argmax_final(const float* __restrict__ pval,
                                                      const int* __restrict__ pidx,
                                                      int* __restrict__ cur_tok,
                                                      float* __restrict__ outs_t) {
  __shared__ float sv[256];
  __shared__ int si[256];
  int b = blockIdx.x, tid = threadIdx.x;
  float bv = -3.402823466e38f;
  int bi = INT_MAX;
  for (int c = tid; c < NCHUNK; c += 256) {
    float v = pval[(size_t)b * NCHUNK + c];
    int i2 = pidx[(size_t)b * NCHUNK + c];
    if (v > bv || (v == bv && i2 < bi)) { bv = v; bi = i2; }
  }
  sv[tid] = bv; si[tid] = bi;
  __syncthreads();
  for (int s = 128; s > 0; s >>= 1) {
    if (tid < s) {
      float v = sv[tid + s]; int i2 = si[tid + s];
      if (v > sv[tid] || (v == sv[tid] && i2 < si[tid])) { sv[tid] = v; si[tid] = i2; }
    }
    __syncthreads();
  }
  if (tid == 0) { cur_tok[b] = si[0]; outs_t[b] = (float)si[0]; }
}

extern "C" void kernel_launch(void* const* d_in, const int* in_sizes, int n_in,
                              void* d_out, int out_size, void* d_ws, size_t ws_size,
                              hipStream_t stream) {
  const float* lang_h0 = (const float*)d_in[0];
  const float* ctx_h   = (const float*)d_in[1];
  const float* emb     = (const float*)d_in[2];
  const float* dec_W   = (const float*)d_in[3];
  const float* dec_b   = (const float*)d_in[4];
  const float* w_ih    = (const float*)d_in[5];
  const float* w_hh    = (const float*)d_in[6];
  const float* b_ih    = (const float*)d_in[7];
  const float* b_hh    = (const float*)d_in[8];
  const int*   inpt0   = (const int*)d_in[9];
  const int*   temp_p  = (const int*)d_in[10];

  float* out = (float*)d_out;
  float* outs = out;                           // [100][512] token ids as f32
  float* Hbase = out + (size_t)T_STEPS * BSZ;  // [102][512][1024]

  uint8_t* ws = (uint8_t*)d_ws;
  uint32_t* keys = (uint32_t*)ws;                               // 800 B
  int* cur_tok = (int*)(ws + 4096);                             // 2 KB
  unsigned short* dh = (unsigned short*)(ws + 8192);            // 512x256 bf16 x3
  unsigned short* dm = dh + (size_t)BSZ * EMB;
  unsigned short* dl = dm + (size_t)BSZ * EMB;
  float* pval = (float*)(dl + (size_t)BSZ * EMB);               // 512x250
  int* pidx = (int*)(pval + (size_t)BSZ * NCHUNK);
  float* Gp = (float*)(pidx + (size_t)BSZ * NCHUNK);            // 512x4096 f32 (8.4 MB)
  unsigned short* xh = (unsigned short*)(Gp + (size_t)BSZ * NCAT);  // 512x1536 x3 (4.7 MB)
  unsigned short* xm = xh + (size_t)BSZ * KCAT;
  unsigned short* xl = xm + (size_t)BSZ * KCAT;
  unsigned short* wch = xl + (size_t)BSZ * KCAT;                // 4096x1536 x3 (37.7 MB)
  unsigned short* wcm = wch + (size_t)NCAT * KCAT;
  unsigned short* wcl = wcm + (size_t)NCAT * KCAT;
  float* bc = (float*)(wcl + (size_t)NCAT * KCAT);              // 16 KB
  unsigned short* ebh = (unsigned short*)(bc + NCAT);           // 32000x256 bf16 x3 (49 MB)
  unsigned short* ebm = ebh + (size_t)VOC * EMB;
  unsigned short* ebl = ebm + (size_t)VOC * EMB;
  // total ws use ~102 MB

  k_wprep<<<(NCAT * KCAT / 4 + 255) / 256, 256, 0, stream>>>(w_ih, w_hh, wch, wcm, wcl);
  k_split3<<<(VOC * EMB / 4 + 255) / 256, 256, 0, stream>>>(emb, ebh, ebm, ebl,
                                                            VOC * EMB / 4);
  k_init<<<(BSZ * HL) / 256, 256, 0, stream>>>(lang_h0, inpt0, b_ih, b_hh,
                                               keys, cur_tok, Hbase, bc);

  for (int t = 0; t <= T_STEPS; t++) {
    const float* Hin = Hbase + (size_t)t * BSZ * HL;
    float* Hout = Hbase + (size_t)(t + 1) * BSZ * HL;
    k_xsplit<<<(BSZ * KCAT / 4 + 255) / 256, 256, 0, stream>>>(emb, ctx_h, cur_tok,
                                                               Hin, xh, xm, xl);
    k_big<<<dim3(NCAT / 64, BSZ / 64), 256, 0, stream>>>(xh, xm, xl, wch, wcm, wcl,
                                                         bc, Gp);
    k_point<<<(BSZ * HL / 4 + 255) / 256, 256, 0, stream>>>(Gp, Hin, Hout);
    if (t == T_STEPS) break;                   // extra writer step: no sampling
    k_dec<<<dim3(4, 32), 256, 0, stream>>>(Hout, dec_W, dec_b, dh, dm, dl);
    k_logits<<<dim3(NCHUNK, 4), 256, 0, stream>>>(dh, dm, dl, ebh, ebm, ebl, keys, t,
                                                  temp_p, pval, pidx);
    k_argmax_final<<<BSZ, 256, 0, stream>>>(pval, pidx, cur_tok, outs + (size_t)t * BSZ);
  }
}

// Round 3
// 29843.375 us; speedup vs baseline: 1.0467x; 1.0467x over previous
//
#include <hip/hip_runtime.h>
#include <stdint.h>
#include <limits.h>

// Problem constants (match reference)
#define T_STEPS 100
#define BSZ 512
#define HL 1024
#define HC 256
#define EMB 256
#define VOC 32000
#define NCHUNK 250           // VOC / 128

typedef __attribute__((ext_vector_type(8))) short short8;
typedef __attribute__((ext_vector_type(4))) float f32x4;
typedef __attribute__((ext_vector_type(4))) unsigned short u16x4;
#define MFMA16(a, b, c) __builtin_amdgcn_mfma_f32_16x16x32_bf16(a, b, c, 0, 0, 0)

// 6-term product of triple-split operands: residual ~2^-24 (fp32-class)
#define ACC6(acc, ah, am, al, bh, bm, bl) \
  { acc = MFMA16(ah, bh, acc); acc = MFMA16(ah, bm, acc); acc = MFMA16(am, bh, acc); \
    acc = MFMA16(ah, bl, acc); acc = MFMA16(am, bm, acc); acc = MFMA16(al, bh, acc); }

// ---------------- threefry2x32 (JAX-exact) ----------------
__device__ __forceinline__ void threefry2x32(uint32_t k0, uint32_t k1,
                                             uint32_t x0, uint32_t x1,
                                             uint32_t& o0, uint32_t& o1) {
  uint32_t ks2 = k0 ^ k1 ^ 0x1BD11BDAu;
  x0 += k0; x1 += k1;
#define TF_R(x, r) (((x) << (r)) | ((x) >> (32 - (r))))
#define TF_RND(r) { x0 += x1; x1 = TF_R(x1, r); x1 ^= x0; }
  TF_RND(13) TF_RND(15) TF_RND(26) TF_RND(6)
  x0 += k1; x1 += ks2 + 1u;
  TF_RND(17) TF_RND(29) TF_RND(16) TF_RND(24)
  x0 += ks2; x1 += k0 + 2u;
  TF_RND(13) TF_RND(15) TF_RND(26) TF_RND(6)
  x0 += k0; x1 += k1 + 3u;
  TF_RND(17) TF_RND(29) TF_RND(16) TF_RND(24)
  x0 += k1; x1 += ks2 + 4u;
  TF_RND(13) TF_RND(15) TF_RND(26) TF_RND(6)
  x0 += ks2; x1 += k0 + 5u;
#undef TF_RND
#undef TF_R
  o0 = x0; o1 = x1;
}

__device__ __forceinline__ float gumbel_from_u32(uint32_t bits) {
  float f = __uint_as_float((bits >> 9) | 0x3f800000u) - 1.0f;
  f = fmaxf(f, 1.17549435e-38f);
  return -logf(-logf(f));
}

__device__ __forceinline__ float read_temp(const int* p) {
  int v = *p;
  if (v >= -(1 << 24) && v <= (1 << 24)) return (float)v;
  return __int_as_float(v);
}

__device__ __forceinline__ unsigned short f2bf(float x) {
  uint32_t u = __float_as_uint(x);
  u += 0x7fffu + ((u >> 16) & 1u);
  return (unsigned short)(u >> 16);
}
__device__ __forceinline__ float bf2f(unsigned short h) {
  return __uint_as_float(((uint32_t)h) << 16);
}
__device__ __forceinline__ void split3(float x, unsigned short& h,
                                       unsigned short& m, unsigned short& l) {
  h = f2bf(x);
  float r = x - bf2f(h);     // exact
  m = f2bf(r);
  r = r - bf2f(m);           // exact
  l = f2bf(r);
}

// token <-> packed low32: low = 0xFFFFFFFF - tok (so smaller tok wins atomicMax at equal score)
__device__ __forceinline__ int unpack_tok(unsigned long long pk) {
  return (int)(0xFFFFFFFFu - (uint32_t)(pk & 0xFFFFFFFFull));
}

// ---------------- fp32 -> bf16 triple split (once: w_ih, emb, ctx) ----------------
__global__ __launch_bounds__(256) void k_split3(const float* __restrict__ src,
                                                unsigned short* __restrict__ hi,
                                                unsigned short* __restrict__ mid,
                                                unsigned short* __restrict__ lo,
                                                int n4) {
  int i = blockIdx.x * 256 + threadIdx.x;
  if (i >= n4) return;
  float4 v = ((const float4*)src)[i];
  float vv[4] = {v.x, v.y, v.z, v.w};
  u16x4 h, m, l;
#pragma unroll
  for (int j = 0; j < 4; j++) {
    unsigned short a, b, c;
    split3(vv[j], a, b, c);
    h[j] = a; m[j] = b; l[j] = c;
  }
  ((u16x4*)hi)[i] = h;
  ((u16x4*)mid)[i] = m;
  ((u16x4*)lo)[i] = l;
}

// ---------------- init: keys, packed token init, H0 copy ----------------
__global__ __launch_bounds__(256) void k_init(const float* __restrict__ lang_h0,
                                              const int* __restrict__ inpt0,
                                              uint32_t* __restrict__ keys,
                                              unsigned long long* __restrict__ packed,
                                              float* __restrict__ H0) {
  int idx = blockIdx.x * 256 + threadIdx.x;
  if (idx < T_STEPS) {
    uint32_t o0, o1;
    threefry2x32(0u, 1u, 0u, (uint32_t)idx, o0, o1);
    keys[2 * idx] = o0; keys[2 * idx + 1] = o1;
  }
  if (idx < BSZ)
    packed[idx] = (unsigned long long)(0xFFFFFFFFu - (uint32_t)inpt0[idx]);
  if (idx < BSZ * HL) H0[idx] = lang_h0[idx];
}

// ---------------- GI = [emb[tok],ctx] @ w_ih^T + b_ih, 6-term MFMA ----------------
// grid (3072/64=48, 512/64=8), 256 thr = 4 waves. Wave: 16 b x 64 n.
// A-side: pure gather of PRE-SPLIT emb (ebh/m/l) and PRE-SPLIT ctx (cxh/m/l).
// Also unpacks sampled token from `packed` and (x==0) writes outs[t-1].
__global__ __launch_bounds__(256) void k_gi(
    const unsigned short* __restrict__ ebh, const unsigned short* __restrict__ ebm,
    const unsigned short* __restrict__ ebl,
    const unsigned short* __restrict__ cxh, const unsigned short* __restrict__ cxm,
    const unsigned short* __restrict__ cxl,
    const unsigned long long* __restrict__ packed,
    const unsigned short* __restrict__ wih_h, const unsigned short* __restrict__ wih_m,
    const unsigned short* __restrict__ wih_l,
    const float* __restrict__ b_ih, float* __restrict__ GI,
    int t, float* __restrict__ outs) {
  int tid = threadIdx.x;
  int wave = tid >> 6, lane = tid & 63;
  int ml = lane & 15, quad = lane >> 4;
  int n0 = blockIdx.x * 64;
  int bA = blockIdx.y * 64 + wave * 16 + ml;
  int myt = unpack_tok(packed[bA]);
  if (blockIdx.x == 0 && quad == 0 && t > 0)
    outs[(size_t)(t - 1) * BSZ + bA] = (float)myt;
  f32x4 acc[4];
#pragma unroll
  for (int tn = 0; tn < 4; tn++) acc[tn] = (f32x4){0.f, 0.f, 0.f, 0.f};

  for (int k0 = 0; k0 < 512; k0 += 32) {
    int k = k0 + quad * 8;
    short8 ah, am_, al;
    if (k < 256) {
      size_t eo = (size_t)myt * 256 + k;
      ah = *(const short8*)(ebh + eo);
      am_ = *(const short8*)(ebm + eo);
      al = *(const short8*)(ebl + eo);
    } else {
      size_t co = (size_t)bA * 256 + (k - 256);
      ah = *(const short8*)(cxh + co);
      am_ = *(const short8*)(cxm + co);
      al = *(const short8*)(cxl + co);
    }
#pragma unroll
    for (int tn = 0; tn < 4; tn++) {
      int n = n0 + tn * 16 + ml;
      size_t off = (size_t)n * 512 + k;
      short8 bh = *(const short8*)(wih_h + off);
      short8 bm = *(const short8*)(wih_m + off);
      short8 bl = *(const short8*)(wih_l + off);
      ACC6(acc[tn], ah, am_, al, bh, bm, bl);
    }
  }
  // C layout: col = lane&15 (n), row = quad*4+reg (b)
  int brow = blockIdx.y * 64 + wave * 16 + quad * 4;
#pragma unroll
  for (int tn = 0; tn < 4; tn++) {
    int n = n0 + tn * 16 + ml;
    float bias = b_ih[n];
#pragma unroll
    for (int reg = 0; reg < 4; reg++)
      GI[(size_t)(brow + reg) * 3072 + n] = acc[tn][reg] + bias;
  }
}

// ---------------- GRU: GH (fp32 vector) + GI add + pointwise, writes Hout ----------------
// grid (1024/32=32, 512/32=16) = 512 blocks, 128 thr -> 2 blocks/CU = 4 waves/CU (full
// VALU issue; the old 64b tile at 256 blocks left 2 of 4 SIMDs idle).
// Block: 32 b x 32 i x 3 gates.
__global__ __launch_bounds__(128) void k_gru(const float* __restrict__ Hin,
                                             const float* __restrict__ w_hh,
                                             const float* __restrict__ b_hh,
                                             const float* __restrict__ GI,
                                             float* __restrict__ Hout) {
  __shared__ __align__(16) float Ah[32][36];
  __shared__ __align__(16) float Wr[32][34];
  __shared__ __align__(16) float Wz[32][34];
  __shared__ __align__(16) float Wn[32][34];
  int tid = threadIdx.x;
  int ti = tid & 15;
  int tb = tid >> 4;          // 0..7 -> 4 b rows each
  int b0 = blockIdx.y * 32, i0 = blockIdx.x * 32;
  int sr = tid >> 3;          // 0..15
  int kq = (tid & 7) * 4;
  float acc[3][4][2] = {};

  for (int k0 = 0; k0 < 1024; k0 += 32) {
#pragma unroll
    for (int i = 0; i < 2; i++) {
      int r = sr + 16 * i;
      float4 h4 = *(const float4*)&Hin[(size_t)(b0 + r) * 1024 + k0 + kq];
      Ah[kq + 0][r] = h4.x; Ah[kq + 1][r] = h4.y; Ah[kq + 2][r] = h4.z; Ah[kq + 3][r] = h4.w;
    }
#pragma unroll
    for (int g = 0; g < 3; g++) {
      float* Wg = (g == 0 ? &Wr[0][0] : g == 1 ? &Wz[0][0] : &Wn[0][0]);
      const float* src = w_hh + (size_t)(g * 1024 + i0) * 1024;
#pragma unroll
      for (int i = 0; i < 2; i++) {
        int r = sr + 16 * i;
        float4 w4 = *(const float4*)&src[(size_t)r * 1024 + k0 + kq];
        Wg[(kq + 0) * 34 + r] = w4.x; Wg[(kq + 1) * 34 + r] = w4.y;
        Wg[(kq + 2) * 34 + r] = w4.z; Wg[(kq + 3) * 34 + r] = w4.w;
      }
    }
    __syncthreads();
#pragma unroll
    for (int kk = 0; kk < 32; kk++) {
      float4 a0 = *(float4*)&Ah[kk][tb * 4];
      float av[4] = {a0.x, a0.y, a0.z, a0.w};
      float2 wr2 = *(float2*)&Wr[kk][ti * 2];
      float2 wz2 = *(float2*)&Wz[kk][ti * 2];
      float2 wn2 = *(float2*)&Wn[kk][ti * 2];
      float wv0[2] = {wr2.x, wr2.y};
      float wv1[2] = {wz2.x, wz2.y};
      float wv2[2] = {wn2.x, wn2.y};
#pragma unroll
      for (int bb = 0; bb < 4; bb++)
#pragma unroll
        for (int j = 0; j < 2; j++) {
          acc[0][bb][j] += av[bb] * wv0[j];
          acc[1][bb][j] += av[bb] * wv1[j];
          acc[2][bb][j] += av[bb] * wv2[j];
        }
    }
    __syncthreads();
  }
  int i = i0 + ti * 2;
  float2 bhr = *(const float2*)&b_hh[i];
  float2 bhz = *(const float2*)&b_hh[1024 + i];
  float2 bhn = *(const float2*)&b_hh[2048 + i];
  float bhrv[2] = {bhr.x, bhr.y}, bhzv[2] = {bhz.x, bhz.y}, bhnv[2] = {bhn.x, bhn.y};
#pragma unroll
  for (int bb = 0; bb < 4; bb++) {
    int b = b0 + tb * 4 + bb;
    float2 gir = *(const float2*)&GI[(size_t)b * 3072 + i];
    float2 giz = *(const float2*)&GI[(size_t)b * 3072 + 1024 + i];
    float2 gin = *(const float2*)&GI[(size_t)b * 3072 + 2048 + i];
    float2 h2 = *(const float2*)&Hin[(size_t)b * 1024 + i];
    float girv[2] = {gir.x, gir.y}, gizv[2] = {giz.x, giz.y}, ginv[2] = {gin.x, gin.y};
    float hv[2] = {h2.x, h2.y}, ov[2];
#pragma unroll
    for (int j = 0; j < 2; j++) {
      float r = 1.0f / (1.0f + expf(-(girv[j] + acc[0][bb][j] + bhrv[j])));
      float z = 1.0f / (1.0f + expf(-(gizv[j] + acc[1][bb][j] + bhzv[j])));
      float n = tanhf(ginv[j] + r * (acc[2][bb][j] + bhnv[j]));
      ov[j] = (1.0f - z) * n + z * hv[j];
    }
    float2 o; o.x = ov[0]; o.y = ov[1];
    *(float2*)&Hout[(size_t)b * 1024 + i] = o;
  }
}

// ---------------- dec GEMM (fp32) + fused triple-split output; zeroes packed ----------------
// grid (256/64=4, 512/16=32), 256 thr. Block: 16 b x 64 cols, K=1024.
__global__ __launch_bounds__(256) void k_dec(const float* __restrict__ H,
                                             const float* __restrict__ dec_W,
                                             const float* __restrict__ dec_b,
                                             unsigned short* __restrict__ dh,
                                             unsigned short* __restrict__ dm,
                                             unsigned short* __restrict__ dl,
                                             unsigned long long* __restrict__ packed) {
  __shared__ __align__(16) float As[32][20];
  __shared__ __align__(16) float Ws[32][68];
  int tid = threadIdx.x;
  int tb = tid >> 4;          // 0..15 = b row
  int tv = tid & 15;          // 4 cols: tv*4
  int col0 = blockIdx.x * 64, row0 = blockIdx.y * 16;
  if (blockIdx.x == 0 && tid < 16) packed[row0 + tid] = 0ull;  // reset for this step's logits
  int srw = tid >> 3;         // 0..31
  int kq = (tid & 7) * 4;
  float acc[4] = {};
  for (int k0 = 0; k0 < 1024; k0 += 32) {
    if (srw < 16) {           // As: 16 rows x 32 k
      float4 a4 = *(const float4*)&H[(size_t)(row0 + srw) * 1024 + k0 + kq];
      As[kq + 0][srw] = a4.x; As[kq + 1][srw] = a4.y; As[kq + 2][srw] = a4.z; As[kq + 3][srw] = a4.w;
    }
#pragma unroll
    for (int i = 0; i < 2; i++) {
      int r = srw + 32 * i;
      float4 w4 = *(const float4*)&dec_W[(size_t)(col0 + r) * 1024 + k0 + kq];
      Ws[kq + 0][r] = w4.x; Ws[kq + 1][r] = w4.y;
      Ws[kq + 2][r] = w4.z; Ws[kq + 3][r] = w4.w;
    }
    __syncthreads();
#pragma unroll
    for (int kk = 0; kk < 32; kk++) {
      float a = As[kk][tb];
      float4 w = *(float4*)&Ws[kk][tv * 4];
      float wv[4] = {w.x, w.y, w.z, w.w};
#pragma unroll
      for (int j = 0; j < 4; j++) acc[j] += a * wv[j];
    }
    __syncthreads();
  }
  int col = col0 + tv * 4;
  float4 b4 = *(const float4*)&dec_b[col];
  float bv[4] = {b4.x, b4.y, b4.z, b4.w};
  u16x4 h, m, l;
#pragma unroll
  for (int j = 0; j < 4; j++) {
    unsigned short a, b, c;
    split3(acc[j] + bv[j], a, b, c);
    h[j] = a; m[j] = b; l[j] = c;
  }
  size_t o = (size_t)(row0 + tb) * 256 + col;
  *(u16x4*)(dh + o) = h;
  *(u16x4*)(dm + o) = m;
  *(u16x4*)(dl + o) = l;
}

// ---------------- logits 6-term MFMA + gumbel + packed atomicMax argmax ----------------
// grid (250, 4), 256 thr = 4 waves. Block: 128 b x 128 v; wave: 32 b (2 m-tiles) x 128 v.
__global__ __launch_bounds__(256) void k_logits(const unsigned short* __restrict__ dh,
                                                const unsigned short* __restrict__ dm,
                                                const unsigned short* __restrict__ dl,
                                                const unsigned short* __restrict__ ebh,
                                                const unsigned short* __restrict__ ebm,
                                                const unsigned short* __restrict__ ebl,
                                                const uint32_t* __restrict__ keys,
                                                int t,
                                                const int* __restrict__ temp_ptr,
                                                unsigned long long* __restrict__ packed) {
  __shared__ __align__(16) unsigned short Eh[128 * 40];
  __shared__ __align__(16) unsigned short Em[128 * 40];
  __shared__ __align__(16) unsigned short El[128 * 40];
  int tid = threadIdx.x;
  int wave = tid >> 6, lane = tid & 63;
  int ml = lane & 15, quad = lane >> 4;
  int c = blockIdx.x;
  int v0 = c * 128;
  int b0 = blockIdx.y * 128;
  f32x4 acc[2][8];
#pragma unroll
  for (int mi = 0; mi < 2; mi++)
#pragma unroll
    for (int tv = 0; tv < 8; tv++) acc[mi][tv] = (f32x4){0.f, 0.f, 0.f, 0.f};

  for (int k0 = 0; k0 < 256; k0 += 32) {
    __syncthreads();
    // stage pre-split emb tile [128 v][32 k] — pure copy
#pragma unroll
    for (int i = 0; i < 4; i++) {
      int idx4 = tid + i * 256;          // 0..1023 u16x4 slots
      int v = idx4 >> 3;
      int k4 = (idx4 & 7) * 4;
      size_t go = (size_t)(v0 + v) * 256 + k0 + k4;
      *(u16x4*)&Eh[v * 40 + k4] = *(const u16x4*)(ebh + go);
      *(u16x4*)&Em[v * 40 + k4] = *(const u16x4*)(ebm + go);
      *(u16x4*)&El[v * 40 + k4] = *(const u16x4*)(ebl + go);
    }
    __syncthreads();
    // A fragments (dec triple-split, global; L2-resident)
    short8 ah[2], am_[2], al[2];
#pragma unroll
    for (int mi = 0; mi < 2; mi++) {
      int brow = b0 + wave * 32 + mi * 16 + ml;
      size_t off = (size_t)brow * 256 + k0 + quad * 8;
      ah[mi] = *(const short8*)(dh + off);
      am_[mi] = *(const short8*)(dm + off);
      al[mi] = *(const short8*)(dl + off);
    }
#pragma unroll
    for (int tv = 0; tv < 8; tv++) {
      int lo = (tv * 16 + ml) * 40 + quad * 8;
      short8 bh = *(const short8*)&Eh[lo];
      short8 bm = *(const short8*)&Em[lo];
      short8 bl = *(const short8*)&El[lo];
#pragma unroll
      for (int mi = 0; mi < 2; mi++)
        ACC6(acc[mi][tv], ah[mi], am_[mi], al[mi], bh, bm, bl);
    }
  }
  float temp = read_temp(temp_ptr);
  uint32_t kk0 = keys[2 * t], kk1 = keys[2 * t + 1];
#pragma unroll
  for (int mi = 0; mi < 2; mi++) {
    float best[4];
    int bidx[4];
#pragma unroll
    for (int reg = 0; reg < 4; reg++) { best[reg] = -3.402823466e38f; bidx[reg] = INT_MAX; }
    // C layout: col (v) = lane&15, row (b) = quad*4+reg
#pragma unroll
    for (int tv = 0; tv < 8; tv++) {
      int v = v0 + tv * 16 + ml;
#pragma unroll
      for (int reg = 0; reg < 4; reg++) {
        int b = b0 + wave * 32 + mi * 16 + quad * 4 + reg;
        uint32_t o0, o1;
        threefry2x32(kk0, kk1, 0u, (uint32_t)(b * VOC + v), o0, o1);
        float s = acc[mi][tv][reg] / temp + gumbel_from_u32(o0 ^ o1);
        if (s > best[reg]) { best[reg] = s; bidx[reg] = v; }
      }
    }
#pragma unroll
    for (int off = 1; off < 16; off <<= 1) {
#pragma unroll
      for (int reg = 0; reg < 4; reg++) {
        float ov = __shfl_xor(best[reg], off, 64);
        int oi = __shfl_xor(bidx[reg], off, 64);
        if (ov > best[reg] || (ov == best[reg] && oi < bidx[reg])) {
          best[reg] = ov; bidx[reg] = oi;
        }
      }
    }
    if (ml == 0) {
#pragma unroll
      for (int reg = 0; reg < 4; reg++) {
        int b = b0 + wave * 32 + mi * 16 + quad * 4 + reg;
        uint32_t u = __float_as_uint(best[reg]);
        uint32_t mp = (u & 0x80000000u) ? ~u : (u | 0x80000000u);  // order-preserving map
        unsigned long long key = ((unsigned long long)mp << 32) |
                                 (unsigned long long)(0xFFFFFFFFu - (uint32_t)bidx[reg]);
        atomicMax(&packed[b], key);
      }
    }
  }
}

extern "C" void kernel_launch(void* const* d_in, const int* in_sizes, int n_in,
                              void* d_out, int out_size, void* d_ws, size_t ws_size,
                              hipStream_t stream) {
  const float* lang_h0 = (const float*)d_in[0];
  const float* ctx_h   = (const float*)d_in[1];
  const float* emb     = (const float*)d_in[2];
  const float* dec_W   = (const float*)d_in[3];
  const float* dec_b   = (const float*)d_in[4];
  const float* w_ih    = (const float*)d_in[5];
  const float* w_hh    = (const float*)d_in[6];
  const float* b_ih    = (const float*)d_in[7];
  const float* b_hh    = (const float*)d_in[8];
  const int*   inpt0   = (const int*)d_in[9];
  const int*   temp_p  = (const int*)d_in[10];

  float* out = (float*)d_out;
  float* outs = out;                           // [100][512] token ids as f32
  float* Hbase = out + (size_t)T_STEPS * BSZ;  // [102][512][1024]

  uint8_t* ws = (uint8_t*)d_ws;
  uint32_t* keys = (uint32_t*)ws;                               // 800 B
  unsigned long long* packed = (unsigned long long*)(ws + 4096); // 512 x u64
  unsigned short* dh = (unsigned short*)(ws + 16384);           // 512x256 bf16 x3
  unsigned short* dm = dh + (size_t)BSZ * EMB;
  unsigned short* dl = dm + (size_t)BSZ * EMB;
  float* GI = (float*)(dl + (size_t)BSZ * EMB);                 // 512x3072 f32 (6 MB)
  unsigned short* wih_h = (unsigned short*)(GI + (size_t)BSZ * 3 * HL);  // 3072x512 x3
  unsigned short* wih_m = wih_h + (size_t)3 * HL * 512;
  unsigned short* wih_l = wih_m + (size_t)3 * HL * 512;
  unsigned short* ebh = wih_l + (size_t)3 * HL * 512;           // 32000x256 bf16 x3 (49 MB)
  unsigned short* ebm = ebh + (size_t)VOC * EMB;
  unsigned short* ebl = ebm + (size_t)VOC * EMB;
  unsigned short* cxh = ebl + (size_t)VOC * EMB;                // 512x256 bf16 x3
  unsigned short* cxm = cxh + (size_t)BSZ * HC;
  unsigned short* cxl = cxm + (size_t)BSZ * HC;
  // total ws use ~67 MB

  k_split3<<<(3 * HL * 512 / 4 + 255) / 256, 256, 0, stream>>>(w_ih, wih_h, wih_m, wih_l,
                                                               3 * HL * 512 / 4);
  k_split3<<<(VOC * EMB / 4 + 255) / 256, 256, 0, stream>>>(emb, ebh, ebm, ebl,
                                                            VOC * EMB / 4);
  k_split3<<<(BSZ * HC / 4 + 255) / 256, 256, 0, stream>>>(ctx_h, cxh, cxm, cxl,
                                                           BSZ * HC / 4);
  k_init<<<(BSZ * HL) / 256, 256, 0, stream>>>(lang_h0, inpt0, keys, packed, Hbase);

  for (int t = 0; t <= T_STEPS; t++) {
    const float* Hin = Hbase + (size_t)t * BSZ * HL;
    float* Hout = Hbase + (size_t)(t + 1) * BSZ * HL;
    k_gi<<<dim3(48, 8), 256, 0, stream>>>(ebh, ebm, ebl, cxh, cxm, cxl, packed,
                                          wih_h, wih_m, wih_l, b_ih, GI, t, outs);
    k_gru<<<dim3(32, 16), 128, 0, stream>>>(Hin, w_hh, b_hh, GI, Hout);
    if (t == T_STEPS) break;                   // extra writer step: no sampling
    k_dec<<<dim3(4, 32), 256, 0, stream>>>(Hout, dec_W, dec_b, dh, dm, dl, packed);
    k_logits<<<dim3(NCHUNK, 4), 256, 0, stream>>>(dh, dm, dl, ebh, ebm, ebl, keys, t,
                                                  temp_p, packed);
  }
}